// Round 6
// baseline (201.858 us; speedup 1.0000x reference)
//
#include <hip/hip_runtime.h>
#include <hip/hip_fp16.h>
#include <math.h>

// Problem dims (fixed)
#define B     4096
#define NIN   512
#define L     16
#define N     512
#define K     32
#define NOUT  256
#define HID   (L * N)          // 8192
#define TOTAL (NIN + L * N)    // 8704
#define BROWS 2                // batch rows per block (entry = 4 B -> 4 blocks/CU)
#define BLOCK 512              // one neuron per thread per layer

typedef __attribute__((ext_vector_type(2))) _Float16 hv2;         // 4 B: 2 fp16 (2 rows)
typedef __attribute__((ext_vector_type(8))) _Float16 h8;          // 16 B: 8 packed fp16 weights
typedef __attribute__((ext_vector_type(8))) unsigned short u16x8; // 16 B: 8 packed u16 offsets

__device__ __forceinline__ float sigmoidf_fast(float z) {
    return 1.0f / (1.0f + __expf(-z));
}

// ---- repack with 32-ary LATIN-TEMPLATE bank scheduling:
//  * entries are 4 B -> bank key = idx & 31 (full 32-bank alphabet).
//  * first occurrence of each key -> slot (key - rot) & 31, rot = neuron & 31:
//    within a contiguous 32-lane group each slot then reads 32 DISTINCT banks
//    wherever counts allow (HW floor, zero excess). Duplicate-key items
//    (E ~ 12/32) spill into leftover holes — local deviations only.
//  * ALL offsets pre-scaled (idx*4 <= 34812 fits u16): ds_read vaddr =
//    loaded halfword, zero shift VALU, hidden AND output layers.
//  Dot product is permutation-invariant -> numerically free.
//  Workspace footprint identical to the proven 1.08 MB layout.
__global__ void repack_kernel(const float* __restrict__ W,
                              const int*   __restrict__ idx,
                              const float* __restrict__ W_out,
                              const int*   __restrict__ idx_out,
                              _Float16* __restrict__ wh,
                              unsigned short* __restrict__ i16,
                              _Float16* __restrict__ who,
                              unsigned short* __restrict__ io16)
{
    const int n = blockIdx.x * 64 + threadIdx.x;
    const int* ip; const float* wp; _Float16* wo; unsigned short* io;
    if (n < HID) {
        ip = idx + (size_t)n * K;      wp = W + (size_t)n * K;
        wo = wh + (size_t)n * K;       io = i16 + (size_t)n * K;
    } else if (n < HID + NOUT) {
        const int m = n - HID;
        ip = idx_out + (size_t)m * K;  wp = W_out + (size_t)m * K;
        wo = who + (size_t)m * K;      io = io16 + (size_t)m * K;
    } else {
        return;
    }
    const int rot = n & 31;

    // vectorized loads (rows are 128 B aligned)
    int ci[K]; float cw[K];
    {
        const int4*   ip4 = (const int4*)ip;
        const float4* wp4 = (const float4*)wp;
#pragma unroll
        for (int q = 0; q < 8; ++q) {
            const int4   a = ip4[q];
            const float4 f = wp4[q];
            ci[q * 4 + 0] = a.x; ci[q * 4 + 1] = a.y;
            ci[q * 4 + 2] = a.z; ci[q * 4 + 3] = a.w;
            cw[q * 4 + 0] = f.x; cw[q * 4 + 1] = f.y;
            cw[q * 4 + 2] = f.z; cw[q * 4 + 3] = f.w;
        }
    }

    unsigned seen = 0, used = 0;
    int sl[K];
#pragma unroll
    for (int j = 0; j < K; ++j) {
        const int key = ci[j] & 31;
        if (!((seen >> key) & 1u)) {          // first occurrence: template slot
            seen |= 1u << key;
            const int s = (key - rot) & 31;
            sl[j] = s; used |= 1u << s;
        } else {
            sl[j] = -1;                        // duplicate key -> spill pass
        }
    }
#pragma unroll
    for (int j = 0; j < K; ++j) {
        int s = sl[j];
        if (s < 0) { s = (int)__builtin_ctz(~used); used |= 1u << s; }
        io[s] = (unsigned short)(ci[j] << 2);  // pre-scaled byte offset
        wo[s] = (_Float16)cw[j];
    }
}

// ---- 8 gathers (ds_read_b32, pre-scaled vaddr), packed fp16 accumulate
// (1x v_pk_fma_f16 per gather: 2 rows), folded into f32 every 8 (group
// rounding ~6e-4 pre-activation — same order as fp16 storage quantization).
#define GROUP8(CI, W8, AX, AY)                                                \
    {                                                                         \
        hv2 aL = {(_Float16)0.f, (_Float16)0.f};                              \
        _Pragma("unroll")                                                     \
        for (int j = 0; j < 8; ++j) {                                         \
            const int c = (int)(CI)[j];                                       \
            const hv2 v = *(const hv2*)((const char*)buf + c);                \
            hv2 wt2; wt2.x = (W8)[j]; wt2.y = (W8)[j];                        \
            aL = __builtin_elementwise_fma(v, wt2, aL);                       \
        }                                                                     \
        AX += (float)aL.x;  AY += (float)aL.y;                                \
    }

#define LAYER(IDXQ, LI)                                                       \
    {                                                                         \
        const h8* wp = (const h8*)(wh + ((size_t)(LI) * N + t) * K);          \
        const h8 w0 = wp[0], w1 = wp[1], w2 = wp[2], w3 = wp[3];              \
        float ax = 0.f, ay = 0.f;                                             \
        GROUP8(IDXQ[0], w0, ax, ay)                                           \
        GROUP8(IDXQ[1], w1, ax, ay)                                           \
        GROUP8(IDXQ[2], w2, ax, ay)                                           \
        GROUP8(IDXQ[3], w3, ax, ay)                                           \
        const float bb = bias[(LI) * N + t];                                  \
        hv2 o;                                                                \
        o.x = (_Float16)sigmoidf_fast(ax + bb);                               \
        o.y = (_Float16)sigmoidf_fast(ay + bb);                               \
        buf[NIN + (LI) * N + t] = o;                                          \
    }

// buf[c] = {row0,row1} fp16 (4 B). 34 KB -> 4 blocks/CU, 32 waves/CU:
// 2x occupancy of the BROWS=4 version, 4 independently-phased blocks per CU
// to overlap one block's LDS read-burst with another's FMA-burst.
__global__ __launch_bounds__(BLOCK, 8)
void ffnet_kernel(const float* __restrict__ x,
                  const float* __restrict__ bias,
                  const float* __restrict__ bias_out,
                  const _Float16*       __restrict__ wh,
                  const unsigned short* __restrict__ i16,
                  const _Float16*       __restrict__ who,
                  const unsigned short* __restrict__ io16,
                  float* __restrict__ out)
{
    __shared__ hv2 buf[TOTAL];   // 34 KB, LDS offset 0 -> vaddr = offset

    const int t  = threadIdx.x;
    const int r0 = blockIdx.x * BROWS;

    // ---- stage x (transposed): thread t owns column t (NIN == BLOCK)
    {
        hv2 v;
        v.x = (_Float16)x[(size_t)(r0 + 0) * NIN + t];
        v.y = (_Float16)x[(size_t)(r0 + 1) * NIN + t];
        buf[t] = v;
    }

    // ---- prefetch layer 0 offsets (latency overlaps the barrier)
    u16x8 ia[4], ib[4];
    {
        const u16x8* ip = (const u16x8*)(i16 + (size_t)t * K);
        ia[0] = ip[0]; ia[1] = ip[1]; ia[2] = ip[2]; ia[3] = ip[3];
    }
    __syncthreads();

    // ---- 16 hidden layers, ping-pong index register sets.
    // Writes go past all reads of the current layer: one barrier per layer.
    for (int l = 0; l < L; l += 2) {
        {   // prefetch odd layer's offsets — lands during even layer's math
            const u16x8* np = (const u16x8*)(i16 + ((size_t)(l + 1) * N + t) * K);
            ib[0] = np[0]; ib[1] = np[1]; ib[2] = np[2]; ib[3] = np[3];
        }
        LAYER(ia, l)
        __syncthreads();

        if (l + 2 < L) {   // prefetch next even layer
            const u16x8* np = (const u16x8*)(i16 + ((size_t)(l + 2) * N + t) * K);
            ia[0] = np[0]; ia[1] = np[1]; ia[2] = np[2]; ia[3] = np[3];
        } else if (t < NOUT) {   // last iteration: prefetch output offsets
            const u16x8* np = (const u16x8*)(io16 + (size_t)t * K);
            ia[0] = np[0]; ia[1] = np[1]; ia[2] = np[2]; ia[3] = np[3];
        }
        LAYER(ib, l + 1)
        __syncthreads();
    }

    // ---- output layer: threads 0..NOUT-1 (offsets already in ia, pre-scaled)
    if (t < NOUT) {
        const h8* wp = (const h8*)(who + (size_t)t * K);
        const h8 w0 = wp[0], w1 = wp[1], w2 = wp[2], w3 = wp[3];

        float ax = 0.f, ay = 0.f;
        GROUP8(ia[0], w0, ax, ay)
        GROUP8(ia[1], w1, ax, ay)
        GROUP8(ia[2], w2, ax, ay)
        GROUP8(ia[3], w3, ax, ay)

        const float bb = bias_out[t];
        out[(size_t)(r0 + 0) * NOUT + t] = sigmoidf_fast(ax + bb);
        out[(size_t)(r0 + 1) * NOUT + t] = sigmoidf_fast(ay + bb);
    }
}

extern "C" void kernel_launch(void* const* d_in, const int* in_sizes, int n_in,
                              void* d_out, int out_size, void* d_ws, size_t ws_size,
                              hipStream_t stream) {
    const float* x     = (const float*)d_in[0];   // (B, NIN)
    const float* W     = (const float*)d_in[1];   // (L, N, K)
    const float* b     = (const float*)d_in[2];   // (L, N)
    const float* W_out = (const float*)d_in[3];   // (NOUT, K)
    const float* b_out = (const float*)d_in[4];   // (NOUT,)
    const int*   idx   = (const int*)d_in[5];     // (L, N, K)
    const int*   idx_o = (const int*)d_in[6];     // (NOUT, K)
    float* out = (float*)d_out;                   // (B, NOUT)

    // workspace layout — IDENTICAL footprint to the proven 1.08 MB baseline
    char* ws = (char*)d_ws;
    _Float16*       wh   = (_Float16*)      (ws);                         // 512 KB
    unsigned short* i16  = (unsigned short*)(ws + 524288);                // 512 KB
    _Float16*       who  = (_Float16*)      (ws + 1048576);               // 16 KB
    unsigned short* io16 = (unsigned short*)(ws + 1048576 + 16384);       // 16 KB

    const int nneur = HID + NOUT;                 // 8448
    repack_kernel<<<dim3((nneur + 63) / 64), dim3(64), 0, stream>>>(
        W, idx, W_out, idx_o, wh, i16, who, io16);

    ffnet_kernel<<<dim3(B / BROWS), dim3(BLOCK), 0, stream>>>(
        x, b, b_out, wh, i16, who, io16, out);
}

// Round 7
// 168.837 us; speedup vs baseline: 1.1956x; 1.1956x over previous
//
#include <hip/hip_runtime.h>
#include <hip/hip_fp16.h>
#include <math.h>

// Problem dims (fixed)
#define B     4096
#define NIN   512
#define L     16
#define N     512
#define K     32
#define NOUT  256
#define HID   (L * N)          // 8192
#define TOTAL (NIN + L * N)    // 8704
#define BROWS 4                // batch rows per block
#define BLOCK 512              // one neuron per thread per layer

typedef __attribute__((ext_vector_type(2))) _Float16 hv2;         // 4 B: 2 fp16
typedef __attribute__((ext_vector_type(8))) _Float16 h8;          // 16 B: 8 packed fp16 weights
typedef __attribute__((ext_vector_type(8))) unsigned short u16x8; // 16 B: 8 packed u16 offsets

// 8 B LDS entry: 4 batch rows of one column as two fp16 pairs
struct alignas(8) hh { hv2 lo, hi; };

__device__ __forceinline__ float sigmoidf_fast(float z) {
    return 1.0f / (1.0f + __expf(-z));
}

// ---- repack: Latin template + CROSS-LANE SPILL MATCHING.
// Template (round-3/5, proven): item with bank-pair key k = idx&15, rank r<2
// -> slot ((k-rot)&15)+16r, rot = n&15. At each slot the 16 lanes of an LDS
// phase then read 16 DISTINCT pairs — zero excess — except where a lane had
// no item for that slot (a HOLE, filled by a surplus item = SPILL).
// NEW: a spill at slot s leaves pair ((s&15)+rot)&15 missing there. The
// missing-pair set at s is derivable from a hole BALLOT (lanes are the
// neurons of the phase group: 16 consecutive n). Each holed lane picks a
// spill whose key is in that set -> it exactly replaces an absent pair ->
// zero excess. Unmatched/duplicate picks keep the old +1 cost.
// Each lane still places only its OWN items -> bijective per neuron ->
// numerically free regardless of the bank model.
__global__ void repack_kernel(const float* __restrict__ W,
                              const int*   __restrict__ idx,
                              const float* __restrict__ W_out,
                              const int*   __restrict__ idx_out,
                              _Float16* __restrict__ wh,
                              unsigned short* __restrict__ i16,
                              _Float16* __restrict__ who,
                              unsigned short* __restrict__ io16)
{
    const int lane = threadIdx.x;                 // 64-thread blocks
    const int n = blockIdx.x * 64 + lane;         // grid*64 == 8448 exactly
    const int* ip; const float* wp; _Float16* wo; unsigned short* io; int scale;
    if (n < HID) {
        ip = idx + (size_t)n * K;      wp = W + (size_t)n * K;
        wo = wh + (size_t)n * K;       io = i16 + (size_t)n * K;   scale = 3;
    } else {
        const int m = n - HID;                    // m < NOUT by construction
        ip = idx_out + (size_t)m * K;  wp = W_out + (size_t)m * K;
        wo = who + (size_t)m * K;      io = io16 + (size_t)m * K;  scale = 0;
    }
    const int rot = n & 15;

    // vectorized loads (rows are 128 B aligned)
    int ci[K]; float cw[K];
    {
        const int4*   ip4 = (const int4*)ip;
        const float4* wp4 = (const float4*)wp;
#pragma unroll
        for (int q = 0; q < 8; ++q) {
            const int4   a = ip4[q];
            const float4 f = wp4[q];
            ci[q * 4 + 0] = a.x; ci[q * 4 + 1] = a.y;
            ci[q * 4 + 2] = a.z; ci[q * 4 + 3] = a.w;
            cw[q * 4 + 0] = f.x; cw[q * 4 + 1] = f.y;
            cw[q * 4 + 2] = f.z; cw[q * 4 + 3] = f.w;
        }
    }

    // ---- template pass: rank within key via packed byte counters; also
    // pack the 4-bit keys (kp0/kp1) for runtime-indexed access w/o scratch.
    unsigned long long r0 = 0, r1 = 0, kp0 = 0, kp1 = 0;
    int sl[K];
    unsigned used = 0;
#pragma unroll
    for (int j = 0; j < K; ++j) {
        const int key = ci[j] & 15;
        if (j < 16) kp0 |= (unsigned long long)key << (4 * j);
        else        kp1 |= (unsigned long long)key << (4 * (j - 16));
        const int sh = (key & 7) << 3;
        int rank;
        if (key < 8) { rank = (int)((r0 >> sh) & 0xff); r0 += 1ull << sh; }
        else         { rank = (int)((r1 >> sh) & 0xff); r1 += 1ull << sh; }
        if (rank < 2) {
            const int s = ((key - rot) & 15) + (rank << 4);
            sl[j] = s; used |= 1u << s;
        } else {
            sl[j] = -1;                    // spill
        }
    }
    const unsigned hm = ~used;             // hole slots (popcount == #spills)
    unsigned sm = 0;                       // spill item mask
#pragma unroll
    for (int j = 0; j < K; ++j) if (sl[j] < 0) sm |= 1u << j;

    // ---- spill-matching pass: per slot, pick a spill whose key is among
    // the slot's MISSING template pairs (from the hole ballot).
    unsigned long long spl0 = 0, spl1 = 0, spl2 = 0, spl3 = 0;  // item->slot, 8b each
    for (int s = 0; s < 32; ++s) {
        const bool holed = (hm >> s) & 1u;
        const unsigned long long bal = __ballot(holed);
        const unsigned slice = (unsigned)((bal >> (lane & 48)) & 0xFFFFull);
        // missing pair at s for holed lane rot_j: ((s&15)+rot_j)&15
        const unsigned shf = (unsigned)(s & 15);
        const unsigned avail =
            ((slice << shf) | (slice >> ((16u - shf) & 15u))) & 0xFFFFu;
        if (holed) {
            unsigned m = sm;
            int b = -1;
            while (m) {
                const int bb = (int)__builtin_ctz(m);
                const unsigned long long sel = (bb & 16) ? kp1 : kp0;
                const int k = (int)((sel >> ((bb & 15) << 2)) & 15);
                if ((avail >> k) & 1u) { b = bb; break; }
                m &= m - 1;
            }
            if (b < 0) b = (int)__builtin_ctz(sm);   // forced (conflicting) place
            sm &= ~(1u << b);
            const unsigned long long w = (unsigned long long)s << ((b & 7) << 3);
            const int hi = b >> 3;
            spl0 = (hi == 0) ? (spl0 | w) : spl0;    // static 4-way select:
            spl1 = (hi == 1) ? (spl1 | w) : spl1;    // no runtime-indexed array
            spl2 = (hi == 2) ? (spl2 | w) : spl2;
            spl3 = (hi == 3) ? (spl3 | w) : spl3;
        }
    }

    // ---- write pass (static j -> static pack selection)
#pragma unroll
    for (int j = 0; j < K; ++j) {
        int s = sl[j];
        if (s < 0) {
            const unsigned long long sp =
                (j >> 3) == 0 ? spl0 : (j >> 3) == 1 ? spl1
              : (j >> 3) == 2 ? spl2 : spl3;
            s = (int)((sp >> ((j & 7) << 3)) & 0x3F);
        }
        io[s] = (unsigned short)(ci[j] << scale);
        wo[s] = (_Float16)cw[j];
    }
}

// ---- issue a batch of 8 gathers into a register array (no FMA dependency:
// lets the compiler keep many ds_reads in flight under fine-grained lgkmcnt)
#define GATHERS(CI, V, SH)                                                    \
    _Pragma("unroll")                                                         \
    for (int j = 0; j < 8; ++j) {                                             \
        const int c = ((int)(CI)[j]) << (SH);                                 \
        (V)[j] = *(const hh*)((const char*)buf + c);                          \
    }

// ---- 8-element packed-fp16 FMA batch folded into f32 (group rounding
// ~6e-4 pre-activation — same order as fp16 storage quantization)
#define FMA8(V, W8, ACC)                                                      \
    {                                                                         \
        hv2 aL = {(_Float16)0.f, (_Float16)0.f};                              \
        hv2 aH = {(_Float16)0.f, (_Float16)0.f};                              \
        _Pragma("unroll")                                                     \
        for (int j = 0; j < 8; ++j) {                                         \
            hv2 wt2; wt2.x = (W8)[j]; wt2.y = (W8)[j];                        \
            aL = __builtin_elementwise_fma((V)[j].lo, wt2, aL);               \
            aH = __builtin_elementwise_fma((V)[j].hi, wt2, aH);               \
        }                                                                     \
        (ACC).x += (float)aL.x;  (ACC).y += (float)aL.y;                      \
        (ACC).z += (float)aH.x;  (ACC).w += (float)aH.y;                      \
    }

// Software-pipelined layer: weights issued first (L2 latency overlaps gather
// issue), 24 gathers in flight before the first FMA, 4th batch issued
// between FMA groups.
#define LAYER(IDXQ, LI)                                                       \
    {                                                                         \
        const h8* wp = (const h8*)(wh + ((size_t)(LI) * N + t) * K);          \
        const h8 w0 = wp[0], w1 = wp[1], w2 = wp[2], w3 = wp[3];              \
        const float bb = bias[(LI) * N + t];                                  \
        hh v0[8], v1[8], v2[8], v3[8];                                        \
        GATHERS(IDXQ[0], v0, 0)                                               \
        GATHERS(IDXQ[1], v1, 0)                                               \
        GATHERS(IDXQ[2], v2, 0)                                               \
        float4 acc = make_float4(0.f, 0.f, 0.f, 0.f);                         \
        FMA8(v0, w0, acc)                                                     \
        GATHERS(IDXQ[3], v3, 0)                                               \
        FMA8(v1, w1, acc)                                                     \
        FMA8(v2, w2, acc)                                                     \
        FMA8(v3, w3, acc)                                                     \
        hh o;                                                                 \
        o.lo.x = (_Float16)sigmoidf_fast(acc.x + bb);                         \
        o.lo.y = (_Float16)sigmoidf_fast(acc.y + bb);                         \
        o.hi.x = (_Float16)sigmoidf_fast(acc.z + bb);                         \
        o.hi.y = (_Float16)sigmoidf_fast(acc.w + bb);                         \
        buf[NIN + (LI) * N + t] = o;                                          \
    }

// buf[c] = {row0..row3} fp16 (8 B). 68 KB -> 2 blocks/CU.
__global__ __launch_bounds__(BLOCK, 4)
void ffnet_kernel(const float* __restrict__ x,
                  const float* __restrict__ bias,
                  const float* __restrict__ bias_out,
                  const _Float16*       __restrict__ wh,
                  const unsigned short* __restrict__ i16,
                  const _Float16*       __restrict__ who,
                  const unsigned short* __restrict__ io16,
                  float* __restrict__ out)
{
    __shared__ hh buf[TOTAL];   // 68 KB, LDS offset 0 -> vaddr = offset

    const int t  = threadIdx.x;
    const int r0 = blockIdx.x * BROWS;

    // ---- stage x (transposed): thread t owns column t (NIN == BLOCK)
    {
        hh v;
        v.lo.x = (_Float16)x[(size_t)(r0 + 0) * NIN + t];
        v.lo.y = (_Float16)x[(size_t)(r0 + 1) * NIN + t];
        v.hi.x = (_Float16)x[(size_t)(r0 + 2) * NIN + t];
        v.hi.y = (_Float16)x[(size_t)(r0 + 3) * NIN + t];
        buf[t] = v;
    }

    // ---- prefetch layer 0 offsets (latency overlaps the barrier)
    u16x8 ia[4], ib[4];
    {
        const u16x8* ip = (const u16x8*)(i16 + (size_t)t * K);
        ia[0] = ip[0]; ia[1] = ip[1]; ia[2] = ip[2]; ia[3] = ip[3];
    }
    __syncthreads();

    // ---- 16 hidden layers, ping-pong index register sets.
    // Writes go past all reads of the current layer: one barrier per layer.
    for (int l = 0; l < L; l += 2) {
        {   // prefetch odd layer's offsets — lands during even layer's math
            const u16x8* np = (const u16x8*)(i16 + ((size_t)(l + 1) * N + t) * K);
            ib[0] = np[0]; ib[1] = np[1]; ib[2] = np[2]; ib[3] = np[3];
        }
        LAYER(ia, l)
        __syncthreads();

        if (l + 2 < L) {   // prefetch next even layer
            const u16x8* np = (const u16x8*)(i16 + ((size_t)(l + 2) * N + t) * K);
            ia[0] = np[0]; ia[1] = np[1]; ia[2] = np[2]; ia[3] = np[3];
        } else if (t < NOUT) {   // last iteration: prefetch output offsets
            const u16x8* np = (const u16x8*)(io16 + (size_t)t * K);
            ia[0] = np[0]; ia[1] = np[1]; ia[2] = np[2]; ia[3] = np[3];
        }
        LAYER(ib, l + 1)
        __syncthreads();
    }

    // ---- output layer: threads 0..NOUT-1 (offsets already in ia, unscaled)
    if (t < NOUT) {
        const h8* wp = (const h8*)(who + (size_t)t * K);
        const h8 w0 = wp[0], w1 = wp[1], w2 = wp[2], w3 = wp[3];
        const float bb = bias_out[t];

        hh v0[8], v1[8], v2[8], v3[8];
        GATHERS(ia[0], v0, 3)
        GATHERS(ia[1], v1, 3)
        GATHERS(ia[2], v2, 3)
        float4 acc = make_float4(0.f, 0.f, 0.f, 0.f);
        FMA8(v0, w0, acc)
        GATHERS(ia[3], v3, 3)
        FMA8(v1, w1, acc)
        FMA8(v2, w2, acc)
        FMA8(v3, w3, acc)

        out[(size_t)(r0 + 0) * NOUT + t] = sigmoidf_fast(acc.x + bb);
        out[(size_t)(r0 + 1) * NOUT + t] = sigmoidf_fast(acc.y + bb);
        out[(size_t)(r0 + 2) * NOUT + t] = sigmoidf_fast(acc.z + bb);
        out[(size_t)(r0 + 3) * NOUT + t] = sigmoidf_fast(acc.w + bb);
    }
}

extern "C" void kernel_launch(void* const* d_in, const int* in_sizes, int n_in,
                              void* d_out, int out_size, void* d_ws, size_t ws_size,
                              hipStream_t stream) {
    const float* x     = (const float*)d_in[0];   // (B, NIN)
    const float* W     = (const float*)d_in[1];   // (L, N, K)
    const float* b     = (const float*)d_in[2];   // (L, N)
    const float* W_out = (const float*)d_in[3];   // (NOUT, K)
    const float* b_out = (const float*)d_in[4];   // (NOUT,)
    const int*   idx   = (const int*)d_in[5];     // (L, N, K)
    const int*   idx_o = (const int*)d_in[6];     // (NOUT, K)
    float* out = (float*)d_out;                   // (B, NOUT)

    // workspace layout — IDENTICAL footprint to the proven 1.08 MB baseline
    char* ws = (char*)d_ws;
    _Float16*       wh   = (_Float16*)      (ws);                         // 512 KB
    unsigned short* i16  = (unsigned short*)(ws + 524288);                // 512 KB
    _Float16*       who  = (_Float16*)      (ws + 1048576);               // 16 KB
    unsigned short* io16 = (unsigned short*)(ws + 1048576 + 16384);       // 16 KB

    const int nneur = HID + NOUT;                 // 8448 == 132 * 64 exactly
    repack_kernel<<<dim3(nneur / 64), dim3(64), 0, stream>>>(
        W, idx, W_out, idx_o, wh, i16, who, io16);

    ffnet_kernel<<<dim3(B / BROWS), dim3(BLOCK), 0, stream>>>(
        x, b, b_out, wh, i16, who, io16, out);
}

// Round 8
// 149.504 us; speedup vs baseline: 1.3502x; 1.1293x over previous
//
#include <hip/hip_runtime.h>
#include <hip/hip_fp16.h>
#include <math.h>

// Problem dims (fixed)
#define B     4096
#define NIN   512
#define L     16
#define N     512
#define K     32
#define NOUT  256
#define HID   (L * N)          // 8192
#define TOTAL (NIN + L * N)    // 8704
#define BROWS 8                // batch rows per block (entry = 16 B)
#define BLOCK 512              // one neuron per thread per layer
#define LDS_BYTES (TOTAL * 16) // 139264 B (gfx950: 160 KB/CU)

typedef __attribute__((ext_vector_type(8))) _Float16 h8;          // 16 B: 8 fp16
typedef __attribute__((ext_vector_type(8))) unsigned short u16x8; // 16 B: 8 packed u16 offsets

__device__ __forceinline__ float sigmoidf_fast(float z) {
    return 1.0f / (1.0f + __expf(-z));
}

// ---- repack with 8-ary LATIN-TEMPLATE bank scheduling:
// 16 B LDS entries -> a gather touches bank-GROUP key = idx & 7 (4 banks).
// Item with key k, within-key rank r < 4 -> slot ((k - rot) & 7) + 8r,
// rot = n & 7: at each slot, any 8 consecutive lanes read 8 DISTINCT
// bank-groups wherever counts allow (the ds_read_b128 floor). Surplus
// (rank >= 4, E~6/32) spills first-fit into holes.
// (Cross-lane spill matching dropped: proven marginal in round 7.)
//  * hidden offsets stored PRE-SCALED by 8 (idx < 8192 -> fits u16);
//    ffnet shifts <<1 for the 16 B entry. Output idx (< 8704) stored raw,
//    shifted <<4 at use (256 threads only).
// Dot product is permutation-invariant -> numerically free.
// Workspace footprint identical to the proven 1.08 MB layout.
__global__ void repack_kernel(const float* __restrict__ W,
                              const int*   __restrict__ idx,
                              const float* __restrict__ W_out,
                              const int*   __restrict__ idx_out,
                              _Float16* __restrict__ wh,
                              unsigned short* __restrict__ i16,
                              _Float16* __restrict__ who,
                              unsigned short* __restrict__ io16)
{
    const int n = blockIdx.x * 64 + threadIdx.x;   // grid*64 == 8448 exactly
    const int* ip; const float* wp; _Float16* wo; unsigned short* io; int scale;
    if (n < HID) {
        ip = idx + (size_t)n * K;      wp = W + (size_t)n * K;
        wo = wh + (size_t)n * K;       io = i16 + (size_t)n * K;   scale = 3;
    } else {
        const int m = n - HID;                     // m < NOUT by construction
        ip = idx_out + (size_t)m * K;  wp = W_out + (size_t)m * K;
        wo = who + (size_t)m * K;      io = io16 + (size_t)m * K;  scale = 0;
    }
    const int rot = n & 7;

    // vectorized loads (rows are 128 B aligned)
    int ci[K]; float cw[K];
    {
        const int4*   ip4 = (const int4*)ip;
        const float4* wp4 = (const float4*)wp;
#pragma unroll
        for (int q = 0; q < 8; ++q) {
            const int4   a = ip4[q];
            const float4 f = wp4[q];
            ci[q * 4 + 0] = a.x; ci[q * 4 + 1] = a.y;
            ci[q * 4 + 2] = a.z; ci[q * 4 + 3] = a.w;
            cw[q * 4 + 0] = f.x; cw[q * 4 + 1] = f.y;
            cw[q * 4 + 2] = f.z; cw[q * 4 + 3] = f.w;
        }
    }

    // rank within key via one u64 of packed byte counters (register-resident)
    unsigned long long cnt = 0;
    int sl[K];
    unsigned used = 0;
#pragma unroll
    for (int j = 0; j < K; ++j) {
        const int key = ci[j] & 7;
        const int sh  = key << 3;
        const int rank = (int)((cnt >> sh) & 0xff);
        cnt += 1ull << sh;
        if (rank < 4) {                 // template slot: unique per (key, rank)
            const int s = ((key - rot) & 7) + (rank << 3);
            sl[j] = s; used |= 1u << s;
        } else {
            sl[j] = -1;                  // surplus -> spill pass
        }
    }
#pragma unroll
    for (int j = 0; j < K; ++j) {
        int s = sl[j];
        if (s < 0) { s = (int)__builtin_ctz(~used); used |= 1u << s; }
        io[s] = (unsigned short)(ci[j] << scale);
        wo[s] = (_Float16)cw[j];
    }
}

// ---- issue a batch of 8 gathers (ds_read_b128) into a register array:
// no FMA dependency -> many reads in flight under fine-grained lgkmcnt.
#define GATHERS(CI, V, SH)                                                    \
    _Pragma("unroll")                                                         \
    for (int j = 0; j < 8; ++j) {                                             \
        const int c = ((int)(CI)[j]) << (SH);                                 \
        (V)[j] = *(const h8*)((const char*)buf + c);                          \
    }

// ---- 8-gather packed-fp16 FMA batch (4 v_pk_fma_f16 per gather: 8 rows),
// folded into f32 every 8 (group rounding ~6e-4 pre-activation — same order
// as the fp16 storage quantization).
#define FMA8(V, W8, FA)                                                       \
    {                                                                         \
        h8 a8 = {(_Float16)0.f, (_Float16)0.f, (_Float16)0.f, (_Float16)0.f, \
                 (_Float16)0.f, (_Float16)0.f, (_Float16)0.f, (_Float16)0.f};\
        _Pragma("unroll")                                                     \
        for (int j = 0; j < 8; ++j) {                                         \
            h8 wt;                                                            \
            _Pragma("unroll")                                                 \
            for (int k = 0; k < 8; ++k) wt[k] = (W8)[j];                      \
            a8 = __builtin_elementwise_fma((V)[j], wt, a8);                   \
        }                                                                     \
        _Pragma("unroll")                                                     \
        for (int r = 0; r < 8; ++r) (FA)[r] += (float)a8[r];                  \
    }

// Software-pipelined layer: weights first (L2 latency overlaps gather issue),
// 24 gathers issued before the first FMA, 4th batch between FMA groups.
// 256-VGPR budget at 2 waves/SIMD -> compiler can honor the batches.
#define LAYER(IDXQ, LI, SH)                                                   \
    {                                                                         \
        const h8* wp = (const h8*)(wh + ((size_t)(LI) * N + t) * K);          \
        const h8 w0 = wp[0], w1 = wp[1], w2 = wp[2], w3 = wp[3];              \
        const float bb = bias[(LI) * N + t];                                  \
        h8 v0[8], v1[8], v2[8], v3[8];                                        \
        GATHERS(IDXQ[0], v0, SH)                                              \
        GATHERS(IDXQ[1], v1, SH)                                              \
        GATHERS(IDXQ[2], v2, SH)                                              \
        float fa[8] = {0.f,0.f,0.f,0.f,0.f,0.f,0.f,0.f};                      \
        FMA8(v0, w0, fa)                                                      \
        GATHERS(IDXQ[3], v3, SH)                                              \
        FMA8(v1, w1, fa)                                                      \
        FMA8(v2, w2, fa)                                                      \
        FMA8(v3, w3, fa)                                                      \
        h8 o;                                                                 \
        _Pragma("unroll")                                                     \
        for (int r = 0; r < 8; ++r)                                           \
            o[r] = (_Float16)sigmoidf_fast(fa[r] + bb);                       \
        buf[NIN + (LI) * N + t] = o;                                          \
    }

// buf[c] = {row0..row7} fp16 (16 B). 136 KB -> 1 block/CU, 8 waves.
// Per layer per thread: 4x dwordx4 idx (ping-pong prefetched) + 4x dwordx4 W
// + 32 ds_read_b128 gathers (8-ary Latin template) + 128 v_pk_fma_f16.
// Half the LDS instructions and half the per-row overhead VALU of the
// BROWS=4 b64 version, for the same work.
__global__ __launch_bounds__(BLOCK, 2)
void ffnet_kernel(const float* __restrict__ x,
                  const float* __restrict__ bias,
                  const float* __restrict__ bias_out,
                  const _Float16*       __restrict__ wh,
                  const unsigned short* __restrict__ i16,
                  const _Float16*       __restrict__ who,
                  const unsigned short* __restrict__ io16,
                  float* __restrict__ out)
{
    extern __shared__ h8 buf[];   // 136 KB, LDS offset 0 -> vaddr = offset

    const int t  = threadIdx.x;
    const int r0 = blockIdx.x * BROWS;

    // ---- stage x (transposed): thread t owns column t (NIN == BLOCK)
    {
        h8 v;
#pragma unroll
        for (int r = 0; r < 8; ++r)
            v[r] = (_Float16)x[(size_t)(r0 + r) * NIN + t];
        buf[t] = v;
    }

    // ---- prefetch layer 0 offsets (latency overlaps the barrier)
    u16x8 ia[4], ib[4];
    {
        const u16x8* ip = (const u16x8*)(i16 + (size_t)t * K);
        ia[0] = ip[0]; ia[1] = ip[1]; ia[2] = ip[2]; ia[3] = ip[3];
    }
    __syncthreads();

    // ---- 16 hidden layers, ping-pong index register sets.
    // Writes go past all reads of the current layer: one barrier per layer.
    for (int l = 0; l < L; l += 2) {
        {   // prefetch odd layer's offsets — lands during even layer's math
            const u16x8* np = (const u16x8*)(i16 + ((size_t)(l + 1) * N + t) * K);
            ib[0] = np[0]; ib[1] = np[1]; ib[2] = np[2]; ib[3] = np[3];
        }
        LAYER(ia, l, 1)
        __syncthreads();

        if (l + 2 < L) {   // prefetch next even layer
            const u16x8* np = (const u16x8*)(i16 + ((size_t)(l + 2) * N + t) * K);
            ia[0] = np[0]; ia[1] = np[1]; ia[2] = np[2]; ia[3] = np[3];
        } else if (t < NOUT) {   // last iteration: prefetch output offsets
            const u16x8* np = (const u16x8*)(io16 + (size_t)t * K);
            ia[0] = np[0]; ia[1] = np[1]; ia[2] = np[2]; ia[3] = np[3];
        }
        LAYER(ib, l + 1, 1)
        __syncthreads();
    }

    // ---- output layer: threads 0..NOUT-1 (offsets already in ia, raw idx)
    if (t < NOUT) {
        const h8* wp = (const h8*)(who + (size_t)t * K);
        const h8 w0 = wp[0], w1 = wp[1], w2 = wp[2], w3 = wp[3];
        const float bb = bias_out[t];

        h8 v0[8], v1[8], v2[8], v3[8];
        GATHERS(ia[0], v0, 4)
        GATHERS(ia[1], v1, 4)
        GATHERS(ia[2], v2, 4)
        float fa[8] = {0.f,0.f,0.f,0.f,0.f,0.f,0.f,0.f};
        FMA8(v0, w0, fa)
        GATHERS(ia[3], v3, 4)
        FMA8(v1, w1, fa)
        FMA8(v2, w2, fa)
        FMA8(v3, w3, fa)

#pragma unroll
        for (int r = 0; r < 8; ++r)
            out[(size_t)(r0 + r) * NOUT + t] = sigmoidf_fast(fa[r] + bb);
    }
}

extern "C" void kernel_launch(void* const* d_in, const int* in_sizes, int n_in,
                              void* d_out, int out_size, void* d_ws, size_t ws_size,
                              hipStream_t stream) {
    const float* x     = (const float*)d_in[0];   // (B, NIN)
    const float* W     = (const float*)d_in[1];   // (L, N, K)
    const float* b     = (const float*)d_in[2];   // (L, N)
    const float* W_out = (const float*)d_in[3];   // (NOUT, K)
    const float* b_out = (const float*)d_in[4];   // (NOUT,)
    const int*   idx   = (const int*)d_in[5];     // (L, N, K)
    const int*   idx_o = (const int*)d_in[6];     // (NOUT, K)
    float* out = (float*)d_out;                   // (B, NOUT)

    // workspace layout — IDENTICAL footprint to the proven 1.08 MB baseline
    char* ws = (char*)d_ws;
    _Float16*       wh   = (_Float16*)      (ws);                         // 512 KB
    unsigned short* i16  = (unsigned short*)(ws + 524288);                // 512 KB
    _Float16*       who  = (_Float16*)      (ws + 1048576);               // 16 KB
    unsigned short* io16 = (unsigned short*)(ws + 1048576 + 16384);       // 16 KB

    const int nneur = HID + NOUT;                 // 8448 == 132 * 64 exactly
    repack_kernel<<<dim3(nneur / 64), dim3(64), 0, stream>>>(
        W, idx, W_out, idx_o, wh, i16, who, io16);

    ffnet_kernel<<<dim3(B / BROWS), dim3(BLOCK), LDS_BYTES, stream>>>(
        x, b, b_out, wh, i16, who, io16, out);
}